// Round 1
// baseline (683.686 us; speedup 1.0000x reference)
//
#include <hip/hip_runtime.h>

#define N_NODES 50000
#define N_EDGES 800000
#define D 64

// Edge-parallel scatter-add: 16 threads per edge, each thread handles 4
// contiguous features (float4 gather from x, 4 float atomicAdds into out).
__global__ __launch_bounds__(256) void spmm_atomic_kernel(
    const float* __restrict__ x,
    const int*   __restrict__ rows,
    const int*   __restrict__ cols,
    const float* __restrict__ vals,
    const float* __restrict__ ws,
    const int*   __restrict__ idx,
    float*       __restrict__ out)
{
    const float w = ws[idx[0]];

    int t = blockIdx.x * blockDim.x + threadIdx.x;
    int e = t >> 4;            // edge index
    int f = (t & 15) << 2;     // feature offset (0,4,...,60)
    if (e >= N_EDGES) return;

    const int   r  = rows[e];
    const int   c  = cols[e];
    const float wv = w * vals[e];

    const float4 xv = *reinterpret_cast<const float4*>(&x[(size_t)c * D + f]);

    float* o = &out[(size_t)r * D + f];
    atomicAdd(o + 0, wv * xv.x);
    atomicAdd(o + 1, wv * xv.y);
    atomicAdd(o + 2, wv * xv.z);
    atomicAdd(o + 3, wv * xv.w);
}

extern "C" void kernel_launch(void* const* d_in, const int* in_sizes, int n_in,
                              void* d_out, int out_size, void* d_ws, size_t ws_size,
                              hipStream_t stream) {
    const float* x    = (const float*)d_in[0];
    const int*   rows = (const int*)d_in[1];
    const int*   cols = (const int*)d_in[2];
    const float* vals = (const float*)d_in[3];
    const float* ws   = (const float*)d_in[4];
    const int*   idx  = (const int*)d_in[5];
    float*       out  = (float*)d_out;

    // out is accumulated into atomically -> must be zeroed every call.
    hipMemsetAsync(out, 0, (size_t)N_NODES * D * sizeof(float), stream);

    const int total_threads = N_EDGES * 16;
    dim3 block(256);
    dim3 grid((total_threads + 255) / 256);
    spmm_atomic_kernel<<<grid, block, 0, stream>>>(x, rows, cols, vals, ws, idx, out);
}

// Round 2
// 196.583 us; speedup vs baseline: 3.4779x; 3.4779x over previous
//
#include <hip/hip_runtime.h>

#define N_NODES 50000
#define N_EDGES 800000
#define D 64

// ---------------- Phase kernels: CSR build + pull gather ----------------

__global__ __launch_bounds__(256) void hist_kernel(
    const int* __restrict__ rows, int* __restrict__ counts)
{
    int e = blockIdx.x * 256 + threadIdx.x;
    if (e < N_EDGES) atomicAdd(&counts[rows[e]], 1);
}

// Single-block exclusive scan of counts[0..N_NODES) -> offsets[0..N_NODES].
// 1024 threads, 4 elements/thread per chunk (4096/chunk, 13 chunks).
__global__ __launch_bounds__(1024) void scan_kernel(
    const int* __restrict__ counts, int* __restrict__ offsets)
{
    __shared__ int sums[1024];
    __shared__ int running_s;
    if (threadIdx.x == 0) running_s = 0;
    __syncthreads();

    const int CHUNK = 4096;
    for (int base = 0; base < N_NODES; base += CHUNK) {
        int i0 = base + threadIdx.x * 4;
        int v[4];
#pragma unroll
        for (int k = 0; k < 4; ++k) {
            int i = i0 + k;
            v[k] = (i < N_NODES) ? counts[i] : 0;
        }
        int s = v[0] + v[1] + v[2] + v[3];
        sums[threadIdx.x] = s;
        __syncthreads();
        // Hillis-Steele inclusive scan over 1024 per-thread sums
        for (int off = 1; off < 1024; off <<= 1) {
            int t = (threadIdx.x >= off) ? sums[threadIdx.x - off] : 0;
            __syncthreads();
            sums[threadIdx.x] += t;
            __syncthreads();
        }
        int incl = sums[threadIdx.x];
        int excl = incl - s;
        int chunk_total = sums[1023];
        int run = running_s;          // stable: last write was before a barrier
        int o = run + excl;
#pragma unroll
        for (int k = 0; k < 4; ++k) {
            int i = i0 + k;
            if (i < N_NODES) offsets[i] = o;
            o += v[k];
        }
        __syncthreads();
        if (threadIdx.x == 0) running_s += chunk_total;
        __syncthreads();
    }
    if (threadIdx.x == 0) offsets[N_NODES] = running_s;
}

__global__ __launch_bounds__(256) void scatter_kernel(
    const int* __restrict__ rows, const int* __restrict__ cols,
    const float* __restrict__ vals, int* __restrict__ cursor,
    int2* __restrict__ edges)
{
    int e = blockIdx.x * 256 + threadIdx.x;
    if (e >= N_EDGES) return;
    int r = rows[e];
    int p = atomicAdd(&cursor[r], 1);
    int2 cv;
    cv.x = cols[e];
    cv.y = __float_as_int(vals[e]);
    edges[p] = cv;
}

// One wave (64 lanes) per node; lane = feature index. Per edge: broadcast
// (col,val) load + coalesced 256B row read of x. Non-atomic coalesced write.
__global__ __launch_bounds__(256) void gather_kernel(
    const float* __restrict__ x, const int2* __restrict__ edges,
    const int* __restrict__ offsets, const float* __restrict__ ws,
    const int* __restrict__ idx, float* __restrict__ out)
{
    const float w = ws[idx[0]];
    int node = blockIdx.x * 4 + (threadIdx.x >> 6);
    int lane = threadIdx.x & 63;
    if (node >= N_NODES) return;

    int beg = offsets[node];
    int end = offsets[node + 1];
    float acc = 0.f;
    int e = beg;
    // 2-wide manual unroll for a bit of load ILP
    for (; e + 1 < end; e += 2) {
        int2 cv0 = edges[e];
        int2 cv1 = edges[e + 1];
        float x0 = x[(size_t)cv0.x * D + lane];
        float x1 = x[(size_t)cv1.x * D + lane];
        acc += __int_as_float(cv0.y) * x0;
        acc += __int_as_float(cv1.y) * x1;
    }
    if (e < end) {
        int2 cv = edges[e];
        acc += __int_as_float(cv.y) * x[(size_t)cv.x * D + lane];
    }
    out[(size_t)node * D + lane] = w * acc;
}

// ---------------- Fallback: round-1 edge-parallel atomic kernel ----------------

__global__ __launch_bounds__(256) void spmm_atomic_kernel(
    const float* __restrict__ x, const int* __restrict__ rows,
    const int* __restrict__ cols, const float* __restrict__ vals,
    const float* __restrict__ ws, const int* __restrict__ idx,
    float* __restrict__ out)
{
    const float w = ws[idx[0]];
    int t = blockIdx.x * blockDim.x + threadIdx.x;
    int e = t >> 4;
    int f = (t & 15) << 2;
    if (e >= N_EDGES) return;
    const int r = rows[e];
    const int c = cols[e];
    const float wv = w * vals[e];
    const float4 xv = *reinterpret_cast<const float4*>(&x[(size_t)c * D + f]);
    float* o = &out[(size_t)r * D + f];
    atomicAdd(o + 0, wv * xv.x);
    atomicAdd(o + 1, wv * xv.y);
    atomicAdd(o + 2, wv * xv.z);
    atomicAdd(o + 3, wv * xv.w);
}

extern "C" void kernel_launch(void* const* d_in, const int* in_sizes, int n_in,
                              void* d_out, int out_size, void* d_ws, size_t ws_size,
                              hipStream_t stream) {
    const float* x    = (const float*)d_in[0];
    const int*   rows = (const int*)d_in[1];
    const int*   cols = (const int*)d_in[2];
    const float* vals = (const float*)d_in[3];
    const float* ws   = (const float*)d_in[4];
    const int*   idx  = (const int*)d_in[5];
    float*       out  = (float*)d_out;

    // ws layout: [edges: E*8B][offsets: (N+1)*4B][counts/cursor: N*4B]
    const size_t edges_bytes   = (size_t)N_EDGES * sizeof(int2);
    const size_t offsets_bytes = (size_t)(N_NODES + 1) * sizeof(int);
    const size_t counts_bytes  = (size_t)N_NODES * sizeof(int);
    const size_t need = edges_bytes + offsets_bytes + counts_bytes;

    if (ws_size < need) {
        // Fallback: atomic scatter (round-1 version).
        hipMemsetAsync(out, 0, (size_t)N_NODES * D * sizeof(float), stream);
        const int total_threads = N_EDGES * 16;
        spmm_atomic_kernel<<<dim3((total_threads + 255) / 256), dim3(256), 0, stream>>>(
            x, rows, cols, vals, ws, idx, out);
        return;
    }

    char* wsb = (char*)d_ws;
    int2* edges   = (int2*)wsb;
    int*  offsets = (int*)(wsb + edges_bytes);
    int*  counts  = (int*)(wsb + edges_bytes + offsets_bytes);  // reused as cursor

    hipMemsetAsync(counts, 0, counts_bytes, stream);

    hist_kernel<<<dim3((N_EDGES + 255) / 256), dim3(256), 0, stream>>>(rows, counts);

    scan_kernel<<<dim3(1), dim3(1024), 0, stream>>>(counts, offsets);

    // cursor := offsets[0..N)
    hipMemcpyAsync(counts, offsets, counts_bytes, hipMemcpyDeviceToDevice, stream);

    scatter_kernel<<<dim3((N_EDGES + 255) / 256), dim3(256), 0, stream>>>(
        rows, cols, vals, counts, edges);

    gather_kernel<<<dim3((N_NODES + 3) / 4), dim3(256), 0, stream>>>(
        x, edges, offsets, ws, idx, out);
}